// Round 1
// baseline (1008.200 us; speedup 1.0000x reference)
//
#include <hip/hip_runtime.h>
#include <hip/hip_bf16.h>

#define NN 50000
#define NE 800000
#define BM 64
#define BN 256
#define BK 16

// ---------------- CSR build ----------------
__global__ void k_zero(int* __restrict__ p, int n) {
  int i = blockIdx.x * blockDim.x + threadIdx.x;
  if (i < n) p[i] = 0;
}

__global__ void k_count(const int* __restrict__ dst, int* __restrict__ cnt) {
  int i = blockIdx.x * blockDim.x + threadIdx.x;
  int st = gridDim.x * blockDim.x;
  for (; i < NE; i += st) atomicAdd(&cnt[dst[i]], 1);
}

// single-block scan: cnt -> exclusive prefix; writes rowptr[0..NN] and turns cnt into a cursor copy
__global__ __launch_bounds__(1024) void k_scan(int* __restrict__ cnt, int* __restrict__ rowptr) {
  __shared__ int wsum[16];
  __shared__ int woff[16];
  __shared__ int tot;
  const int tid = threadIdx.x;
  const int lane = tid & 63;
  const int w = tid >> 6;
  int running = 0;
  for (int base = 0; base < NN; base += 1024) {
    int i = base + tid;
    int v = (i < NN) ? cnt[i] : 0;
    int x = v;
#pragma unroll
    for (int off = 1; off < 64; off <<= 1) {
      int t = __shfl_up(x, off);
      if (lane >= off) x += t;
    }
    if (lane == 63) wsum[w] = x;
    __syncthreads();
    if (w == 0) {
      int s = (lane < 16) ? wsum[lane] : 0;
#pragma unroll
      for (int off = 1; off < 16; off <<= 1) {
        int t = __shfl_up(s, off);
        if (lane >= off) s += t;
      }
      if (lane < 16) woff[lane] = s - wsum[lane];
      if (lane == 15) tot = s;
    }
    __syncthreads();
    if (i < NN) {
      int excl = running + woff[w] + (x - v);
      rowptr[i] = excl;
      cnt[i] = excl;  // cursor copy for fill
    }
    running += tot;
    __syncthreads();
  }
  if (tid == 0) rowptr[NN] = running;
}

__global__ void k_fill(const int* __restrict__ src, const int* __restrict__ dst,
                       int* __restrict__ cursor, int* __restrict__ col) {
  int i = blockIdx.x * blockDim.x + threadIdx.x;
  int st = gridDim.x * blockDim.x;
  for (; i < NE; i += st) {
    int p = atomicAdd(&cursor[dst[i]], 1);
    col[p] = src[i];
  }
}

// ---------------- mean aggregation (CSR, one wave per node) ----------------
template <int D>
__global__ __launch_bounds__(256) void k_agg(const float* __restrict__ h,
                                             const int* __restrict__ rowptr,
                                             const int* __restrict__ col,
                                             float* __restrict__ hn) {
  constexpr int VEC = D / 64;  // floats per lane
  const int lane = threadIdx.x & 63;
  const int n = blockIdx.x * 4 + (threadIdx.x >> 6);
  if (n >= NN) return;
  const int start = rowptr[n];
  const int end = rowptr[n + 1];
  float acc[VEC];
#pragma unroll
  for (int t = 0; t < VEC; ++t) acc[t] = 0.f;
  for (int base = start; base < end; base += 64) {
    int e = base + lane;
    int c = (e < end) ? col[e] : 0;
    int m = min(64, end - base);
    for (int t = 0; t < m; ++t) {
      int cs = __shfl(c, t);
      const float* hp = h + (size_t)cs * D + lane * VEC;
      if constexpr (VEC == 4) {
        float4 v = *reinterpret_cast<const float4*>(hp);
        acc[0] += v.x; acc[1] += v.y; acc[2] += v.z; acc[3] += v.w;
      } else {
        float2 v = *reinterpret_cast<const float2*>(hp);
        acc[0] += v.x; acc[1] += v.y;
      }
    }
  }
  int deg = end - start;
  float sc = 1.0f / (float)(deg > 0 ? deg : 1);
  float* op = hn + (size_t)n * D + lane * VEC;
  if constexpr (VEC == 4) {
    *reinterpret_cast<float4*>(op) =
        make_float4(acc[0] * sc, acc[1] * sc, acc[2] * sc, acc[3] * sc);
  } else {
    *reinterpret_cast<float2*>(op) = make_float2(acc[0] * sc, acc[1] * sc);
  }
}

// ---------------- fused dual GEMM + bias + relu ----------------
// out[m, :] = relu(A1[m,:K1] @ W1 + A2[m,:K2] @ W2 + bias), W row-major [K][256]
// In-place safe for out==A1: each block reads only its own BM rows, writes after all reads.
__global__ __launch_bounds__(256, 2) void k_gemm2(
    const float* __restrict__ A1, const float* __restrict__ W1, int K1,
    const float* __restrict__ A2, const float* __restrict__ W2, int K2,
    const float* __restrict__ bias, float* __restrict__ out) {
  __shared__ __align__(16) float Wt[BK][BN + 4];
  __shared__ __align__(16) float At[BK][BM + 4];
  const int tid = threadIdx.x;
  const int tx = tid & 31;   // col group: cols tx*8 .. tx*8+7
  const int ty = tid >> 5;   // row group: rows ty*8 .. ty*8+7
  const int m0 = blockIdx.x * BM;

  float acc[8][8];
#pragma unroll
  for (int i = 0; i < 8; ++i)
#pragma unroll
    for (int j = 0; j < 8; ++j) acc[i][j] = 0.f;

  const int lr = tid >> 6;  // W tile: base row 0..3
  const int lc = tid & 63;  // W tile: float4 col 0..63
  const int am = tid >> 2;  // A tile: row 0..63
  const int ak = tid & 3;   // A tile: k-quad 0..3

  for (int phase = 0; phase < 2; ++phase) {
    const float* A = phase ? A2 : A1;
    const float* W = phase ? W2 : W1;
    const int K = phase ? K2 : K1;
    for (int k0 = 0; k0 < K; k0 += BK) {
      __syncthreads();
#pragma unroll
      for (int rr = 0; rr < BK; rr += 4) {
        float4 wv = *reinterpret_cast<const float4*>(&W[(size_t)(k0 + lr + rr) * BN + lc * 4]);
        *reinterpret_cast<float4*>(&Wt[lr + rr][lc * 4]) = wv;
      }
      {
        int row = m0 + am;
        float4 av = make_float4(0.f, 0.f, 0.f, 0.f);
        if (row < NN) av = *reinterpret_cast<const float4*>(&A[(size_t)row * K + k0 + ak * 4]);
        At[ak * 4 + 0][am] = av.x;
        At[ak * 4 + 1][am] = av.y;
        At[ak * 4 + 2][am] = av.z;
        At[ak * 4 + 3][am] = av.w;
      }
      __syncthreads();
#pragma unroll
      for (int kk = 0; kk < BK; ++kk) {
        float4 a0 = *reinterpret_cast<const float4*>(&At[kk][ty * 8]);
        float4 a1 = *reinterpret_cast<const float4*>(&At[kk][ty * 8 + 4]);
        float4 w0 = *reinterpret_cast<const float4*>(&Wt[kk][tx * 8]);
        float4 w1 = *reinterpret_cast<const float4*>(&Wt[kk][tx * 8 + 4]);
        float a[8] = {a0.x, a0.y, a0.z, a0.w, a1.x, a1.y, a1.z, a1.w};
        float wv[8] = {w0.x, w0.y, w0.z, w0.w, w1.x, w1.y, w1.z, w1.w};
#pragma unroll
        for (int i = 0; i < 8; ++i)
#pragma unroll
          for (int j = 0; j < 8; ++j) acc[i][j] += a[i] * wv[j];
      }
    }
  }

  float bb[8];
#pragma unroll
  for (int j = 0; j < 8; ++j) bb[j] = bias[tx * 8 + j];
#pragma unroll
  for (int i = 0; i < 8; ++i) {
    int row = m0 + ty * 8 + i;
    if (row < NN) {
      float o[8];
#pragma unroll
      for (int j = 0; j < 8; ++j) {
        float v = acc[i][j] + bb[j];
        o[j] = v > 0.f ? v : 0.f;
      }
      *reinterpret_cast<float4*>(&out[(size_t)row * BN + tx * 8]) =
          make_float4(o[0], o[1], o[2], o[3]);
      *reinterpret_cast<float4*>(&out[(size_t)row * BN + tx * 8 + 4]) =
          make_float4(o[4], o[5], o[6], o[7]);
    }
  }
}

extern "C" void kernel_launch(void* const* d_in, const int* in_sizes, int n_in,
                              void* d_out, int out_size, void* d_ws, size_t ws_size,
                              hipStream_t stream) {
  const float* x   = (const float*)d_in[0];
  const int* src   = (const int*)d_in[1];
  const int* dst   = (const int*)d_in[2];
  const float* Ws0 = (const float*)d_in[3];
  const float* Wn0 = (const float*)d_in[4];
  const float* b0  = (const float*)d_in[5];
  const float* Ws1 = (const float*)d_in[6];
  const float* Wn1 = (const float*)d_in[7];
  const float* b1  = (const float*)d_in[8];
  const float* Ws2 = (const float*)d_in[9];
  const float* Wn2 = (const float*)d_in[10];
  const float* b2  = (const float*)d_in[11];
  float* out = (float*)d_out;

  char* ws = (char*)d_ws;
  size_t off = 0;
  float* H  = (float*)(ws + off); off += (size_t)NN * 256 * sizeof(float);
  float* HN = (float*)(ws + off); off += (size_t)NN * 256 * sizeof(float);
  int* rowptr = (int*)(ws + off); off += (size_t)(NN + 1) * sizeof(int);
  off = (off + 255) & ~(size_t)255;
  int* cnt = (int*)(ws + off); off += (size_t)NN * sizeof(int);
  off = (off + 255) & ~(size_t)255;
  int* col = (int*)(ws + off); off += (size_t)NE * sizeof(int);

  // CSR build (per launch; ws is re-poisoned before every call)
  k_zero<<<(NN + 1023) / 1024, 1024, 0, stream>>>(cnt, NN);
  k_count<<<1024, 256, 0, stream>>>(dst, cnt);
  k_scan<<<1, 1024, 0, stream>>>(cnt, rowptr);
  k_fill<<<1024, 256, 0, stream>>>(src, dst, cnt, col);

  const int aggGrid = (NN + 3) / 4;
  const int gemmGrid = (NN + BM - 1) / BM;

  // layer 0 (D_IN = 128)
  k_agg<128><<<aggGrid, 256, 0, stream>>>(x, rowptr, col, HN);
  k_gemm2<<<gemmGrid, 256, 0, stream>>>(x, Ws0, 128, HN, Wn0, 128, b0, H);
  // layer 1
  k_agg<256><<<aggGrid, 256, 0, stream>>>(H, rowptr, col, HN);
  k_gemm2<<<gemmGrid, 256, 0, stream>>>(H, Ws1, 256, HN, Wn1, 256, b1, H);
  // layer 2
  k_agg<256><<<aggGrid, 256, 0, stream>>>(H, rowptr, col, HN);
  k_gemm2<<<gemmGrid, 256, 0, stream>>>(H, Ws2, 256, HN, Wn2, 256, b2, out);
}

// Round 3
// 936.545 us; speedup vs baseline: 1.0765x; 1.0765x over previous
//
#include <hip/hip_runtime.h>
#include <hip/hip_bf16.h>

#define NN 50000
#define NE 800000

typedef __attribute__((ext_vector_type(8))) short short8v;
typedef __attribute__((ext_vector_type(4))) float f32x4;

__device__ __forceinline__ ushort f2b(float f) {
  uint u = __float_as_uint(f);
  return (ushort)((u + 0x7FFFu + ((u >> 16) & 1u)) >> 16);
}
__device__ __forceinline__ float b2f(ushort h) {
  return __uint_as_float(((uint)h) << 16);
}
__device__ __forceinline__ void gload_lds16(const void* g, void* l) {
  __builtin_amdgcn_global_load_lds((const __attribute__((address_space(1))) void*)g,
                                   (__attribute__((address_space(3))) void*)l, 16, 0, 0);
}

// ---------------- CSR build ----------------
__global__ void k_zero(int* __restrict__ p, int n) {
  int i = blockIdx.x * blockDim.x + threadIdx.x;
  if (i < n) p[i] = 0;
}

__global__ void k_count(const int* __restrict__ dst, int* __restrict__ cnt) {
  int i = blockIdx.x * blockDim.x + threadIdx.x;
  int st = gridDim.x * blockDim.x;
  for (; i < NE; i += st) atomicAdd(&cnt[dst[i]], 1);
}

__global__ __launch_bounds__(1024) void k_scan(int* __restrict__ cnt, int* __restrict__ rowptr) {
  __shared__ int wsum[16];
  __shared__ int woff[16];
  __shared__ int tot;
  const int tid = threadIdx.x;
  const int lane = tid & 63;
  const int w = tid >> 6;
  int running = 0;
  for (int base = 0; base < NN; base += 1024) {
    int i = base + tid;
    int v = (i < NN) ? cnt[i] : 0;
    int x = v;
#pragma unroll
    for (int off = 1; off < 64; off <<= 1) {
      int t = __shfl_up(x, off);
      if (lane >= off) x += t;
    }
    if (lane == 63) wsum[w] = x;
    __syncthreads();
    if (w == 0) {
      int s = (lane < 16) ? wsum[lane] : 0;
#pragma unroll
      for (int off = 1; off < 16; off <<= 1) {
        int t = __shfl_up(s, off);
        if (lane >= off) s += t;
      }
      if (lane < 16) woff[lane] = s - wsum[lane];
      if (lane == 15) tot = s;
    }
    __syncthreads();
    if (i < NN) {
      int excl = running + woff[w] + (x - v);
      rowptr[i] = excl;
      cnt[i] = excl;
    }
    running += tot;
    __syncthreads();
  }
  if (tid == 0) rowptr[NN] = running;
}

__global__ void k_fill(const int* __restrict__ src, const int* __restrict__ dst,
                       int* __restrict__ cursor, int* __restrict__ col) {
  int i = blockIdx.x * blockDim.x + threadIdx.x;
  int st = gridDim.x * blockDim.x;
  for (; i < NE; i += st) {
    int p = atomicAdd(&cursor[dst[i]], 1);
    col[p] = src[i];
  }
}

// ---------------- weight transpose + hi/lo split: Wt[c][k] ----------------
__global__ void k_wprep(const float* __restrict__ W, ushort* __restrict__ Th,
                        ushort* __restrict__ Tl, int K, int logK) {
  int t = blockIdx.x * blockDim.x + threadIdx.x;
  if (t >= (K << 8)) return;
  int k = t & (K - 1);
  int c = t >> logK;
  float v = W[(size_t)k * 256 + c];
  ushort h = f2b(v);
  Th[(size_t)c * K + k] = h;
  Tl[(size_t)c * K + k] = f2b(v - b2f(h));
}

// ---------------- x -> bf16 hi/lo planes (stride 256, cols 0..127) ----------------
__global__ void k_split(const float* __restrict__ x, ushort* __restrict__ Sh,
                        ushort* __restrict__ Sl) {
  int t = blockIdx.x * blockDim.x + threadIdx.x;
  if (t >= NN * 32) return;
  int r = t >> 5, q = t & 31;
  float4 v = *reinterpret_cast<const float4*>(x + (size_t)r * 128 + q * 4);
  ushort4 h, l;
  h.x = f2b(v.x); l.x = f2b(v.x - b2f(h.x));
  h.y = f2b(v.y); l.y = f2b(v.y - b2f(h.y));
  h.z = f2b(v.z); l.z = f2b(v.z - b2f(h.z));
  h.w = f2b(v.w); l.w = f2b(v.w - b2f(h.w));
  *reinterpret_cast<ushort4*>(Sh + (size_t)r * 256 + q * 4) = h;
  *reinterpret_cast<ushort4*>(Sl + (size_t)r * 256 + q * 4) = l;
}

// ---------------- aggregation: fp32 x (D=128) -> bf16 planes ----------------
__global__ __launch_bounds__(256) void k_agg_x(const float* __restrict__ x,
                                               const int* __restrict__ rowptr,
                                               const int* __restrict__ col,
                                               ushort* __restrict__ Nh,
                                               ushort* __restrict__ Nl) {
  const int lane = threadIdx.x & 63;
  const int n = blockIdx.x * 4 + (threadIdx.x >> 6);
  if (n >= NN) return;
  const int start = rowptr[n];
  const int end = rowptr[n + 1];
  float a0 = 0.f, a1 = 0.f;
  for (int base = start; base < end; base += 64) {
    int e = base + lane;
    int c = (e < end) ? col[e] : 0;
    int m = min(64, end - base);
    for (int t = 0; t < m; ++t) {
      int cs = __shfl(c, t);
      float2 v = *reinterpret_cast<const float2*>(x + (size_t)cs * 128 + lane * 2);
      a0 += v.x;
      a1 += v.y;
    }
  }
  int deg = end - start;
  float sc = 1.0f / (float)(deg > 0 ? deg : 1);
  a0 *= sc; a1 *= sc;
  ushort2 hh, ll;
  hh.x = f2b(a0); ll.x = f2b(a0 - b2f(hh.x));
  hh.y = f2b(a1); ll.y = f2b(a1 - b2f(hh.y));
  *reinterpret_cast<ushort2*>(Nh + (size_t)n * 256 + lane * 2) = hh;
  *reinterpret_cast<ushort2*>(Nl + (size_t)n * 256 + lane * 2) = ll;
}

// ---------------- aggregation: bf16 hi/lo planes (D=256) -> bf16 planes ----------------
__global__ __launch_bounds__(256) void k_agg_b(const ushort* __restrict__ Sh,
                                               const ushort* __restrict__ Sl,
                                               const int* __restrict__ rowptr,
                                               const int* __restrict__ col,
                                               ushort* __restrict__ Nh,
                                               ushort* __restrict__ Nl) {
  const int lane = threadIdx.x & 63;
  const int n = blockIdx.x * 4 + (threadIdx.x >> 6);
  if (n >= NN) return;
  const int start = rowptr[n];
  const int end = rowptr[n + 1];
  float acc0 = 0.f, acc1 = 0.f, acc2 = 0.f, acc3 = 0.f;
  for (int base = start; base < end; base += 64) {
    int e = base + lane;
    int c = (e < end) ? col[e] : 0;
    int m = min(64, end - base);
    for (int t = 0; t < m; ++t) {
      int cs = __shfl(c, t);
      const size_t ro = (size_t)cs * 256 + lane * 4;
      ushort4 vh = *reinterpret_cast<const ushort4*>(Sh + ro);
      ushort4 vl = *reinterpret_cast<const ushort4*>(Sl + ro);
      acc0 += b2f(vh.x) + b2f(vl.x);
      acc1 += b2f(vh.y) + b2f(vl.y);
      acc2 += b2f(vh.z) + b2f(vl.z);
      acc3 += b2f(vh.w) + b2f(vl.w);
    }
  }
  int deg = end - start;
  float sc = 1.0f / (float)(deg > 0 ? deg : 1);
  acc0 *= sc; acc1 *= sc; acc2 *= sc; acc3 *= sc;
  ushort4 hh, ll;
  hh.x = f2b(acc0); ll.x = f2b(acc0 - b2f(hh.x));
  hh.y = f2b(acc1); ll.y = f2b(acc1 - b2f(hh.y));
  hh.z = f2b(acc2); ll.z = f2b(acc2 - b2f(hh.z));
  hh.w = f2b(acc3); ll.w = f2b(acc3 - b2f(hh.w));
  const size_t oo = (size_t)n * 256 + lane * 4;
  *reinterpret_cast<ushort4*>(Nh + oo) = hh;
  *reinterpret_cast<ushort4*>(Nl + oo) = ll;
}

// ---------------- MFMA dual-GEMM: relu(A1*W1 + A2*W2 + b) ----------------
// A planes: [NN][256] bf16 hi/lo (row-local in-place output is race-free).
// W planes: transposed Wt[c][k], staged fragment-major into LDS via global_load_lds.
__global__ __launch_bounds__(256) void k_mfma(
    const ushort* __restrict__ A1h, const ushort* __restrict__ A1l,
    const ushort* __restrict__ A2h, const ushort* __restrict__ A2l,
    const ushort* __restrict__ W1h, const ushort* __restrict__ W1l,
    const ushort* __restrict__ W2h, const ushort* __restrict__ W2l,
    const float* __restrict__ bias, int K1, int K2,
    float* __restrict__ outF, ushort* __restrict__ outH, ushort* __restrict__ outL) {
  __shared__ ushort Bls[2][16 * 512];  // [plane][frag c*512 + lane*8], 32 KB
  const int tid = threadIdx.x;
  const int w = tid >> 6;
  const int lane = tid & 63;
  const int m0 = blockIdx.x * 64;
  const int lrow = lane & 15;
  const int kg8 = (lane >> 4) * 8;

  f32x4 acc[4][4];
#pragma unroll
  for (int i = 0; i < 4; ++i)
#pragma unroll
    for (int j = 0; j < 4; ++j) acc[i][j] = (f32x4){0.f, 0.f, 0.f, 0.f};

  for (int ph = 0; ph < 2; ++ph) {
    const ushort* Ah = ph ? A2h : A1h;
    const ushort* Al = ph ? A2l : A1l;
    const ushort* Wh = ph ? W2h : W1h;
    const ushort* Wl = ph ? W2l : W1l;
    const int K = ph ? K2 : K1;
    for (int k0 = 0; k0 < K; k0 += 32) {
      __syncthreads();  // previous step's ds_reads complete before overwrite
#pragma unroll
      for (int j = 0; j < 4; ++j) {
        const int c = w * 4 + j;
        const size_t go = (size_t)(c * 16 + lrow) * K + k0 + kg8;
        gload_lds16(Wh + go, (void*)&Bls[0][c * 512]);
        gload_lds16(Wl + go, (void*)&Bls[1][c * 512]);
      }
      short8v ah[4], al[4];
#pragma unroll
      for (int rf = 0; rf < 4; ++rf) {
        int row = m0 + rf * 16 + lrow;
        row = row < NN ? row : NN - 1;
        const size_t ao = (size_t)row * 256 + k0 + kg8;
        ah[rf] = *reinterpret_cast<const short8v*>(Ah + ao);
        al[rf] = *reinterpret_cast<const short8v*>(Al + ao);
      }
      __syncthreads();  // drains vmcnt(0): LDS tile + A frags ready
      short8v bh[4], bl[4];
#pragma unroll
      for (int cf = 0; cf < 4; ++cf) {
        bh[cf] = *reinterpret_cast<const short8v*>(&Bls[0][(w * 4 + cf) * 512 + lane * 8]);
        bl[cf] = *reinterpret_cast<const short8v*>(&Bls[1][(w * 4 + cf) * 512 + lane * 8]);
      }
#pragma unroll
      for (int rf = 0; rf < 4; ++rf)
#pragma unroll
        for (int cf = 0; cf < 4; ++cf) {
          acc[rf][cf] = __builtin_amdgcn_mfma_f32_16x16x32_bf16(ah[rf], bh[cf], acc[rf][cf], 0, 0, 0);
          acc[rf][cf] = __builtin_amdgcn_mfma_f32_16x16x32_bf16(ah[rf], bl[cf], acc[rf][cf], 0, 0, 0);
          acc[rf][cf] = __builtin_amdgcn_mfma_f32_16x16x32_bf16(al[rf], bh[cf], acc[rf][cf], 0, 0, 0);
        }
    }
  }
  __syncthreads();  // all A reads complete before in-place writes

#pragma unroll
  for (int cf = 0; cf < 4; ++cf) {
    const int colc = w * 64 + cf * 16 + lrow;
    const float bb = bias[colc];
#pragma unroll
    for (int rf = 0; rf < 4; ++rf) {
#pragma unroll
      for (int j = 0; j < 4; ++j) {
        const int row = m0 + rf * 16 + (lane >> 4) * 4 + j;
        if (row < NN) {
          float v = acc[rf][cf][j] + bb;
          v = v > 0.f ? v : 0.f;
          if (outF) {
            outF[(size_t)row * 256 + colc] = v;
          } else {
            ushort h = f2b(v);
            outH[(size_t)row * 256 + colc] = h;
            outL[(size_t)row * 256 + colc] = f2b(v - b2f(h));
          }
        }
      }
    }
  }
}

extern "C" void kernel_launch(void* const* d_in, const int* in_sizes, int n_in,
                              void* d_out, int out_size, void* d_ws, size_t ws_size,
                              hipStream_t stream) {
  const float* x   = (const float*)d_in[0];
  const int* src   = (const int*)d_in[1];
  const int* dst   = (const int*)d_in[2];
  const float* Ws0 = (const float*)d_in[3];
  const float* Wn0 = (const float*)d_in[4];
  const float* b0  = (const float*)d_in[5];
  const float* Ws1 = (const float*)d_in[6];
  const float* Wn1 = (const float*)d_in[7];
  const float* b1  = (const float*)d_in[8];
  const float* Ws2 = (const float*)d_in[9];
  const float* Wn2 = (const float*)d_in[10];
  const float* b2  = (const float*)d_in[11];
  float* out = (float*)d_out;

  char* ws = (char*)d_ws;
  size_t off = 0;
  auto alloc = [&](size_t bytes) {
    void* p = ws + off;
    off = (off + bytes + 255) & ~(size_t)255;
    return p;
  };
  ushort* Sh = (ushort*)alloc((size_t)NN * 256 * 2);
  ushort* Sl = (ushort*)alloc((size_t)NN * 256 * 2);
  ushort* Nh = (ushort*)alloc((size_t)NN * 256 * 2);
  ushort* Nl = (ushort*)alloc((size_t)NN * 256 * 2);
  int* rowptr = (int*)alloc((size_t)(NN + 1) * sizeof(int));
  int* cnt = (int*)alloc((size_t)NN * sizeof(int));
  int* col = (int*)alloc((size_t)NE * sizeof(int));
  ushort* W0sh = (ushort*)alloc(256 * 128 * 2); ushort* W0sl = (ushort*)alloc(256 * 128 * 2);
  ushort* W0nh = (ushort*)alloc(256 * 128 * 2); ushort* W0nl = (ushort*)alloc(256 * 128 * 2);
  ushort* W1sh = (ushort*)alloc(256 * 256 * 2); ushort* W1sl = (ushort*)alloc(256 * 256 * 2);
  ushort* W1nh = (ushort*)alloc(256 * 256 * 2); ushort* W1nl = (ushort*)alloc(256 * 256 * 2);
  ushort* W2sh = (ushort*)alloc(256 * 256 * 2); ushort* W2sl = (ushort*)alloc(256 * 256 * 2);
  ushort* W2nh = (ushort*)alloc(256 * 256 * 2); ushort* W2nl = (ushort*)alloc(256 * 256 * 2);

  // CSR build
  k_zero<<<(NN + 1023) / 1024, 1024, 0, stream>>>(cnt, NN);
  k_count<<<1024, 256, 0, stream>>>(dst, cnt);
  k_scan<<<1, 1024, 0, stream>>>(cnt, rowptr);
  k_fill<<<1024, 256, 0, stream>>>(src, dst, cnt, col);

  // weight prep (transpose + hi/lo split)
  k_wprep<<<128, 256, 0, stream>>>(Ws0, W0sh, W0sl, 128, 7);
  k_wprep<<<128, 256, 0, stream>>>(Wn0, W0nh, W0nl, 128, 7);
  k_wprep<<<256, 256, 0, stream>>>(Ws1, W1sh, W1sl, 256, 8);
  k_wprep<<<256, 256, 0, stream>>>(Wn1, W1nh, W1nl, 256, 8);
  k_wprep<<<256, 256, 0, stream>>>(Ws2, W2sh, W2sl, 256, 8);
  k_wprep<<<256, 256, 0, stream>>>(Wn2, W2nh, W2nl, 256, 8);

  // x -> S planes
  k_split<<<(NN * 32 + 255) / 256, 256, 0, stream>>>(x, Sh, Sl);

  const int aggGrid = (NN + 3) / 4;
  const int gemmGrid = (NN + 63) / 64;

  // layer 0
  k_agg_x<<<aggGrid, 256, 0, stream>>>(x, rowptr, col, Nh, Nl);
  k_mfma<<<gemmGrid, 256, 0, stream>>>(Sh, Sl, Nh, Nl, W0sh, W0sl, W0nh, W0nl,
                                       b0, 128, 128, nullptr, Sh, Sl);
  // layer 1
  k_agg_b<<<aggGrid, 256, 0, stream>>>(Sh, Sl, rowptr, col, Nh, Nl);
  k_mfma<<<gemmGrid, 256, 0, stream>>>(Sh, Sl, Nh, Nl, W1sh, W1sl, W1nh, W1nl,
                                       b1, 256, 256, nullptr, Sh, Sl);
  // layer 2
  k_agg_b<<<aggGrid, 256, 0, stream>>>(Sh, Sl, rowptr, col, Nh, Nl);
  k_mfma<<<gemmGrid, 256, 0, stream>>>(Sh, Sl, Nh, Nl, W2sh, W2sl, W2nh, W2nl,
                                       b2, 256, 256, out, nullptr, nullptr);
}

// Round 6
// 613.821 us; speedup vs baseline: 1.6425x; 1.5258x over previous
//
#include <hip/hip_runtime.h>
#include <hip/hip_bf16.h>

#define NN 50000
#define NE 800000

typedef __attribute__((ext_vector_type(8))) _Float16 half8v;
typedef __attribute__((ext_vector_type(4))) _Float16 half4v;
typedef __attribute__((ext_vector_type(2))) _Float16 half2v;
typedef __attribute__((ext_vector_type(4))) float f32x4;

__device__ __forceinline__ void gload_lds16(const void* g, void* l) {
  __builtin_amdgcn_global_load_lds((const __attribute__((address_space(1))) void*)g,
                                   (__attribute__((address_space(3))) void*)l, 16, 0, 0);
}

// ---------------- CSR build ----------------
__global__ void k_zero(int* __restrict__ p, int n) {
  int i = blockIdx.x * blockDim.x + threadIdx.x;
  if (i < n) p[i] = 0;
}

__global__ void k_count(const int* __restrict__ dst, int* __restrict__ cnt) {
  int i = blockIdx.x * blockDim.x + threadIdx.x;
  int st = gridDim.x * blockDim.x;
  for (; i < NE; i += st) atomicAdd(&cnt[dst[i]], 1);
}

__global__ __launch_bounds__(1024) void k_scan(int* __restrict__ cnt, int* __restrict__ rowptr) {
  __shared__ int wsum[16];
  __shared__ int woff[16];
  __shared__ int tot;
  const int tid = threadIdx.x;
  const int lane = tid & 63;
  const int w = tid >> 6;
  int running = 0;
  for (int base = 0; base < NN; base += 1024) {
    int i = base + tid;
    int v = (i < NN) ? cnt[i] : 0;
    int x = v;
#pragma unroll
    for (int off = 1; off < 64; off <<= 1) {
      int t = __shfl_up(x, off);
      if (lane >= off) x += t;
    }
    if (lane == 63) wsum[w] = x;
    __syncthreads();
    if (w == 0) {
      int s = (lane < 16) ? wsum[lane] : 0;
#pragma unroll
      for (int off = 1; off < 16; off <<= 1) {
        int t = __shfl_up(s, off);
        if (lane >= off) s += t;
      }
      if (lane < 16) woff[lane] = s - wsum[lane];
      if (lane == 15) tot = s;
    }
    __syncthreads();
    if (i < NN) {
      int excl = running + woff[w] + (x - v);
      rowptr[i] = excl;
      cnt[i] = excl;
    }
    running += tot;
    __syncthreads();
  }
  if (tid == 0) rowptr[NN] = running;
}

__global__ void k_fill(const int* __restrict__ src, const int* __restrict__ dst,
                       int* __restrict__ cursor, int* __restrict__ col) {
  int i = blockIdx.x * blockDim.x + threadIdx.x;
  int st = gridDim.x * blockDim.x;
  for (; i < NE; i += st) {
    int p = atomicAdd(&cursor[dst[i]], 1);
    col[p] = src[i];
  }
}

// ---------------- weight transpose to fp16: Wt[c][k] = W[k][c] ----------------
__global__ void k_wprep16(const float* __restrict__ W, _Float16* __restrict__ Wt, int K) {
  int t = blockIdx.x * blockDim.x + threadIdx.x;
  if (t >= (K << 8)) return;
  int c = t & 255;
  int k = t >> 8;
  Wt[(size_t)c * K + k] = (_Float16)W[(size_t)k * 256 + c];
}

// ---------------- x (fp32 [NN][128]) -> fp16 [NN][128] ----------------
__global__ void k_split16(const float* __restrict__ x, _Float16* __restrict__ X16) {
  int t = blockIdx.x * blockDim.x + threadIdx.x;
  if (t >= NN * 16) return;
  const float* p = x + (size_t)t * 8;
  float4 v0 = *reinterpret_cast<const float4*>(p);
  float4 v1 = *reinterpret_cast<const float4*>(p + 4);
  half8v o;
  o[0] = (_Float16)v0.x; o[1] = (_Float16)v0.y; o[2] = (_Float16)v0.z; o[3] = (_Float16)v0.w;
  o[4] = (_Float16)v1.x; o[5] = (_Float16)v1.y; o[6] = (_Float16)v1.z; o[7] = (_Float16)v1.w;
  *reinterpret_cast<half8v*>(X16 + (size_t)t * 8) = o;
}

// ---------------- aggregation: fp32 x (D=128) -> fp16 N [NN][128] ----------------
__global__ __launch_bounds__(256) void k_agg_x16(const float* __restrict__ x,
                                                 const int* __restrict__ rowptr,
                                                 const int* __restrict__ col,
                                                 _Float16* __restrict__ N) {
  const int lane = threadIdx.x & 63;
  const int n = blockIdx.x * 4 + (threadIdx.x >> 6);
  if (n >= NN) return;
  const int start = rowptr[n];
  const int end = rowptr[n + 1];
  float a0 = 0.f, a1 = 0.f;
  for (int base = start; base < end; base += 64) {
    int e = base + lane;
    int c = (e < end) ? col[e] : 0;
    int m = min(64, end - base);
    for (int t = 0; t < m; ++t) {
      int cs = __shfl(c, t);
      float2 v = *reinterpret_cast<const float2*>(x + (size_t)cs * 128 + lane * 2);
      a0 += v.x;
      a1 += v.y;
    }
  }
  int deg = end - start;
  float sc = 1.0f / (float)(deg > 0 ? deg : 1);
  half2v o;
  o[0] = (_Float16)(a0 * sc);
  o[1] = (_Float16)(a1 * sc);
  *reinterpret_cast<half2v*>(N + (size_t)n * 128 + lane * 2) = o;
}

// ---------------- aggregation: fp16 H (D=256) -> fp16 N [NN][256] ----------------
__global__ __launch_bounds__(256) void k_agg16(const _Float16* __restrict__ H,
                                               const int* __restrict__ rowptr,
                                               const int* __restrict__ col,
                                               _Float16* __restrict__ N) {
  const int lane = threadIdx.x & 63;
  const int n = blockIdx.x * 4 + (threadIdx.x >> 6);
  if (n >= NN) return;
  const int start = rowptr[n];
  const int end = rowptr[n + 1];
  float a0 = 0.f, a1 = 0.f, a2 = 0.f, a3 = 0.f;
  for (int base = start; base < end; base += 64) {
    int e = base + lane;
    int c = (e < end) ? col[e] : 0;
    int m = min(64, end - base);
    for (int t = 0; t < m; ++t) {
      int cs = __shfl(c, t);
      half4v v = *reinterpret_cast<const half4v*>(H + (size_t)cs * 256 + lane * 4);
      a0 += (float)v[0];
      a1 += (float)v[1];
      a2 += (float)v[2];
      a3 += (float)v[3];
    }
  }
  int deg = end - start;
  float sc = 1.0f / (float)(deg > 0 ? deg : 1);
  half4v o;
  o[0] = (_Float16)(a0 * sc);
  o[1] = (_Float16)(a1 * sc);
  o[2] = (_Float16)(a2 * sc);
  o[3] = (_Float16)(a3 * sc);
  *reinterpret_cast<half4v*>(N + (size_t)n * 256 + lane * 4) = o;
}

// ---------------- fp16 MFMA dual-GEMM: relu(A1*W1 + A2*W2 + b) ----------------
// A1,A2: [NN][K] fp16. W1t,W2t: [256][K] fp16 (transposed). One of outH/outF non-null.
// T3-minimal pipeline: 1 barrier per k-step, B LDS double-buffered, A regs ping-pong.
__global__ __launch_bounds__(256) void k_mfma16(
    const _Float16* __restrict__ A1, const _Float16* __restrict__ A2,
    const _Float16* __restrict__ W1t, const _Float16* __restrict__ W2t,
    const float* __restrict__ bias, int K,
    _Float16* __restrict__ outH, float* __restrict__ outF) {
  __shared__ _Float16 LDS[16896];  // 2 x 16KB B-tile dbuf; reused as 64x264 out tile
  const int tid = threadIdx.x;
  const int w = tid >> 6;
  const int lane = tid & 63;
  const int lrow = lane & 15;
  const int kg8 = (lane >> 4) * 8;
  const int m0 = blockIdx.x * 64;
  const int nk = K >> 5;       // k-steps per phase
  const int nsteps = nk * 2;   // dual phases (self then neighbor)

  f32x4 acc[4][4];
#pragma unroll
  for (int i = 0; i < 4; ++i)
#pragma unroll
    for (int j = 0; j < 4; ++j) acc[i][j] = (f32x4){0.f, 0.f, 0.f, 0.f};

  size_t aoff[4];
#pragma unroll
  for (int rf = 0; rf < 4; ++rf) {
    int row = m0 + rf * 16 + lrow;
    aoff[rf] = (size_t)(row < NN ? row : NN - 1) * K;
  }

#define STAGEB(S, B)                                                           \
  {                                                                            \
    const _Float16* Wp = ((S) >= nk) ? W2t : W1t;                              \
    const int k0s = (((S) >= nk) ? (S) - nk : (S)) << 5;                       \
    _Pragma("unroll") for (int j = 0; j < 4; ++j) {                            \
      const int c = w * 4 + j;                                                 \
      gload_lds16(Wp + (size_t)(c * 16 + lrow) * K + k0s + kg8,                \
                  (void*)&LDS[(B) * 8192 + c * 512]);                          \
    }                                                                          \
  }

#define LOADA(S, AR)                                                           \
  {                                                                            \
    const _Float16* Ap = ((S) >= nk) ? A2 : A1;                                \
    const int k0a = (((S) >= nk) ? (S) - nk : (S)) << 5;                       \
    _Pragma("unroll") for (int rf = 0; rf < 4; ++rf)                           \
        AR[rf] = *reinterpret_cast<const half8v*>(Ap + aoff[rf] + k0a + kg8);  \
  }

#define COMPUTE(B, AR)                                                         \
  {                                                                            \
    _Pragma("unroll") for (int cf = 0; cf < 4; ++cf) {                         \
      half8v bfr = *reinterpret_cast<const half8v*>(                           \
          &LDS[(B) * 8192 + (w * 4 + cf) * 512 + lane * 8]);                   \
      _Pragma("unroll") for (int rf = 0; rf < 4; ++rf)                         \
          acc[rf][cf] = __builtin_amdgcn_mfma_f32_16x16x32_f16(                \
              AR[rf], bfr, acc[rf][cf], 0, 0, 0);                              \
    }                                                                          \
  }

  half8v aA[4], aB[4];
  STAGEB(0, 0);
  LOADA(0, aA);
  __syncthreads();  // vmcnt(0) drained by compiler before s_barrier
  for (int s = 0; s < nsteps; s += 2) {
    STAGEB(s + 1, 1);   // prefetch next B-tile (hides under COMPUTE)
    LOADA(s + 1, aB);   // prefetch next A frags
    COMPUTE(0, aA);
    __syncthreads();
    if (s + 2 < nsteps) {
      STAGEB(s + 2, 0);
      LOADA(s + 2, aA);
    }
    COMPUTE(1, aB);
    __syncthreads();
  }
#undef STAGEB
#undef LOADA
#undef COMPUTE

  const int rquad = (lane >> 4) * 4;
  if (outF) {
    // final layer: fp32 stores; 16 lanes x 4B = 64B full-line segments
#pragma unroll
    for (int cf = 0; cf < 4; ++cf) {
      const int colc = w * 64 + cf * 16 + lrow;
      const float bb = bias[colc];
#pragma unroll
      for (int rf = 0; rf < 4; ++rf)
#pragma unroll
        for (int j = 0; j < 4; ++j) {
          const int row = m0 + rf * 16 + rquad + j;
          if (row < NN) {
            float v = acc[rf][cf][j] + bb;
            outF[(size_t)row * 256 + colc] = v > 0.f ? v : 0.f;
          }
        }
    }
  } else {
    // fp16 layers: stage tile in LDS (stride 264 halfs), then coalesced 16B stores
#pragma unroll
    for (int cf = 0; cf < 4; ++cf) {
      const int colc = w * 64 + cf * 16 + lrow;
      const float bb = bias[colc];
#pragma unroll
      for (int rf = 0; rf < 4; ++rf)
#pragma unroll
        for (int j = 0; j < 4; ++j) {
          float v = acc[rf][cf][j] + bb;
          LDS[(rf * 16 + rquad + j) * 264 + colc] = (_Float16)(v > 0.f ? v : 0.f);
        }
    }
    __syncthreads();
    const int row = tid >> 2;
    const int q = tid & 3;
    if (m0 + row < NN) {
#pragma unroll
      for (int it = 0; it < 8; ++it)
        *reinterpret_cast<half8v*>(outH + (size_t)(m0 + row) * 256 + q * 64 + it * 8) =
            *reinterpret_cast<const half8v*>(&LDS[row * 264 + q * 64 + it * 8]);
    }
  }
}

extern "C" void kernel_launch(void* const* d_in, const int* in_sizes, int n_in,
                              void* d_out, int out_size, void* d_ws, size_t ws_size,
                              hipStream_t stream) {
  const float* x   = (const float*)d_in[0];
  const int* src   = (const int*)d_in[1];
  const int* dst   = (const int*)d_in[2];
  const float* Ws0 = (const float*)d_in[3];
  const float* Wn0 = (const float*)d_in[4];
  const float* b0  = (const float*)d_in[5];
  const float* Ws1 = (const float*)d_in[6];
  const float* Wn1 = (const float*)d_in[7];
  const float* b1  = (const float*)d_in[8];
  const float* Ws2 = (const float*)d_in[9];
  const float* Wn2 = (const float*)d_in[10];
  const float* b2  = (const float*)d_in[11];
  float* out = (float*)d_out;

  char* ws = (char*)d_ws;
  size_t off = 0;
  auto alloc = [&](size_t bytes) {
    void* p = ws + off;
    off = (off + bytes + 255) & ~(size_t)255;
    return p;
  };
  _Float16* X16 = (_Float16*)alloc((size_t)NN * 128 * 2);
  _Float16* H   = (_Float16*)alloc((size_t)NN * 256 * 2);
  _Float16* Nb  = (_Float16*)alloc((size_t)NN * 256 * 2);
  int* rowptr = (int*)alloc((size_t)(NN + 1) * sizeof(int));
  int* cnt    = (int*)alloc((size_t)NN * sizeof(int));
  int* col    = (int*)alloc((size_t)NE * sizeof(int));
  _Float16* W0s = (_Float16*)alloc(256 * 128 * 2);
  _Float16* W0n = (_Float16*)alloc(256 * 128 * 2);
  _Float16* W1s = (_Float16*)alloc(256 * 256 * 2);
  _Float16* W1n = (_Float16*)alloc(256 * 256 * 2);
  _Float16* W2s = (_Float16*)alloc(256 * 256 * 2);
  _Float16* W2n = (_Float16*)alloc(256 * 256 * 2);

  // CSR build
  k_zero<<<(NN + 1023) / 1024, 1024, 0, stream>>>(cnt, NN);
  k_count<<<1024, 256, 0, stream>>>(dst, cnt);
  k_scan<<<1, 1024, 0, stream>>>(cnt, rowptr);
  k_fill<<<1024, 256, 0, stream>>>(src, dst, cnt, col);

  // weight prep (transpose to [c][k], fp16)
  k_wprep16<<<128, 256, 0, stream>>>(Ws0, W0s, 128);
  k_wprep16<<<128, 256, 0, stream>>>(Wn0, W0n, 128);
  k_wprep16<<<256, 256, 0, stream>>>(Ws1, W1s, 256);
  k_wprep16<<<256, 256, 0, stream>>>(Wn1, W1n, 256);
  k_wprep16<<<256, 256, 0, stream>>>(Ws2, W2s, 256);
  k_wprep16<<<256, 256, 0, stream>>>(Wn2, W2n, 256);

  // x -> fp16
  k_split16<<<(NN * 16 + 255) / 256, 256, 0, stream>>>(x, X16);

  const int aggGrid = (NN + 3) / 4;
  const int gemmGrid = (NN + 63) / 64;

  // layer 0 (K=128)
  k_agg_x16<<<aggGrid, 256, 0, stream>>>(x, rowptr, col, Nb);
  k_mfma16<<<gemmGrid, 256, 0, stream>>>(X16, Nb, W0s, W0n, b0, 128, H, nullptr);
  // layer 1 (K=256)
  k_agg16<<<aggGrid, 256, 0, stream>>>(H, rowptr, col, Nb);
  k_mfma16<<<gemmGrid, 256, 0, stream>>>(H, Nb, W1s, W1n, b1, 256, H, nullptr);
  // layer 2 (K=256) -> fp32 out
  k_agg16<<<aggGrid, 256, 0, stream>>>(H, rowptr, col, Nb);
  k_mfma16<<<gemmGrid, 256, 0, stream>>>(H, Nb, W2s, W2n, b2, 256, nullptr, out);
}

// Round 7
// 505.725 us; speedup vs baseline: 1.9936x; 1.2137x over previous
//
#include <hip/hip_runtime.h>
#include <hip/hip_bf16.h>

#define NN 50000
#define NE 800000

typedef __attribute__((ext_vector_type(8))) _Float16 half8v;
typedef __attribute__((ext_vector_type(4))) _Float16 half4v;
typedef __attribute__((ext_vector_type(2))) _Float16 half2v;
typedef __attribute__((ext_vector_type(4))) float f32x4;

__device__ __forceinline__ void gload_lds16(const void* g, void* l) {
  __builtin_amdgcn_global_load_lds((const __attribute__((address_space(1))) void*)g,
                                   (__attribute__((address_space(3))) void*)l, 16, 0, 0);
}
__device__ __forceinline__ void vm_wait5() {
  asm volatile("s_waitcnt vmcnt(5)" ::: "memory");
  __builtin_amdgcn_sched_barrier(0);
}
__device__ __forceinline__ void vm_wait0() {
  asm volatile("s_waitcnt vmcnt(0)" ::: "memory");
  __builtin_amdgcn_sched_barrier(0);
}
__device__ __forceinline__ void barx() {
  __builtin_amdgcn_sched_barrier(0);
  __builtin_amdgcn_s_barrier();
  __builtin_amdgcn_sched_barrier(0);
}

// ---------------- CSR build ----------------
__global__ void k_zero(int* __restrict__ p, int n) {
  int i = blockIdx.x * blockDim.x + threadIdx.x;
  if (i < n) p[i] = 0;
}

__global__ void k_count(const int* __restrict__ dst, int* __restrict__ cnt) {
  int i = blockIdx.x * blockDim.x + threadIdx.x;
  int st = gridDim.x * blockDim.x;
  for (; i < NE; i += st) atomicAdd(&cnt[dst[i]], 1);
}

__global__ __launch_bounds__(1024) void k_scan(int* __restrict__ cnt, int* __restrict__ rowptr) {
  __shared__ int wsum[16];
  __shared__ int woff[16];
  __shared__ int tot;
  const int tid = threadIdx.x;
  const int lane = tid & 63;
  const int w = tid >> 6;
  int running = 0;
  for (int base = 0; base < NN; base += 1024) {
    int i = base + tid;
    int v = (i < NN) ? cnt[i] : 0;
    int x = v;
#pragma unroll
    for (int off = 1; off < 64; off <<= 1) {
      int t = __shfl_up(x, off);
      if (lane >= off) x += t;
    }
    if (lane == 63) wsum[w] = x;
    __syncthreads();
    if (w == 0) {
      int s = (lane < 16) ? wsum[lane] : 0;
#pragma unroll
      for (int off = 1; off < 16; off <<= 1) {
        int t = __shfl_up(s, off);
        if (lane >= off) s += t;
      }
      if (lane < 16) woff[lane] = s - wsum[lane];
      if (lane == 15) tot = s;
    }
    __syncthreads();
    if (i < NN) {
      int excl = running + woff[w] + (x - v);
      rowptr[i] = excl;
      cnt[i] = excl;
    }
    running += tot;
    __syncthreads();
  }
  if (tid == 0) rowptr[NN] = running;
}

__global__ void k_fill(const int* __restrict__ src, const int* __restrict__ dst,
                       int* __restrict__ cursor, int* __restrict__ col) {
  int i = blockIdx.x * blockDim.x + threadIdx.x;
  int st = gridDim.x * blockDim.x;
  for (; i < NE; i += st) {
    int p = atomicAdd(&cursor[dst[i]], 1);
    col[p] = src[i];
  }
}

// ---------------- weight pack: fragment-major fp16 ----------------
// Wp[(kb*16 + c)*512 + l*8 + i] = W[kb*32 + (l>>4)*8 + i][c*16 + (l&15)]
// One thread writes 8 contiguous halfs at Wp + t*8.
__global__ void k_wpack(const float* __restrict__ W, _Float16* __restrict__ Wp, int K) {
  int t = blockIdx.x * blockDim.x + threadIdx.x;
  if (t >= K * 32) return;
  int l = t & 63;
  int c = (t >> 6) & 15;
  int kb = t >> 10;
  int row = c * 16 + (l & 15);
  int k = kb * 32 + (l >> 4) * 8;
  half8v o;
#pragma unroll
  for (int i = 0; i < 8; ++i) o[i] = (_Float16)W[(size_t)(k + i) * 256 + row];
  *reinterpret_cast<half8v*>(Wp + (size_t)t * 8) = o;
}

// ---------------- x (fp32 [NN][128]) -> fp16 [NN][128] ----------------
__global__ void k_split16(const float* __restrict__ x, _Float16* __restrict__ X16) {
  int t = blockIdx.x * blockDim.x + threadIdx.x;
  if (t >= NN * 16) return;
  const float* p = x + (size_t)t * 8;
  float4 v0 = *reinterpret_cast<const float4*>(p);
  float4 v1 = *reinterpret_cast<const float4*>(p + 4);
  half8v o;
  o[0] = (_Float16)v0.x; o[1] = (_Float16)v0.y; o[2] = (_Float16)v0.z; o[3] = (_Float16)v0.w;
  o[4] = (_Float16)v1.x; o[5] = (_Float16)v1.y; o[6] = (_Float16)v1.z; o[7] = (_Float16)v1.w;
  *reinterpret_cast<half8v*>(X16 + (size_t)t * 8) = o;
}

// ---------------- aggregation: fp32 x (D=128) -> fp16 N [NN][128] ----------------
__global__ __launch_bounds__(256) void k_agg_x16(const float* __restrict__ x,
                                                 const int* __restrict__ rowptr,
                                                 const int* __restrict__ col,
                                                 _Float16* __restrict__ N) {
  const int lane = threadIdx.x & 63;
  const int n = blockIdx.x * 4 + (threadIdx.x >> 6);
  if (n >= NN) return;
  const int start = rowptr[n];
  const int end = rowptr[n + 1];
  float a0 = 0.f, a1 = 0.f;
  for (int base = start; base < end; base += 64) {
    int e = base + lane;
    int c = (e < end) ? col[e] : 0;
    int m = min(64, end - base);
    int t = 0;
    for (; t + 3 < m; t += 4) {
      int c0 = __shfl(c, t), c1 = __shfl(c, t + 1), c2 = __shfl(c, t + 2), c3 = __shfl(c, t + 3);
      float2 v0 = *reinterpret_cast<const float2*>(x + (size_t)c0 * 128 + lane * 2);
      float2 v1 = *reinterpret_cast<const float2*>(x + (size_t)c1 * 128 + lane * 2);
      float2 v2 = *reinterpret_cast<const float2*>(x + (size_t)c2 * 128 + lane * 2);
      float2 v3 = *reinterpret_cast<const float2*>(x + (size_t)c3 * 128 + lane * 2);
      a0 += v0.x + v1.x + v2.x + v3.x;
      a1 += v0.y + v1.y + v2.y + v3.y;
    }
    for (; t < m; ++t) {
      int cs = __shfl(c, t);
      float2 v = *reinterpret_cast<const float2*>(x + (size_t)cs * 128 + lane * 2);
      a0 += v.x;
      a1 += v.y;
    }
  }
  int deg = end - start;
  float sc = 1.0f / (float)(deg > 0 ? deg : 1);
  half2v o;
  o[0] = (_Float16)(a0 * sc);
  o[1] = (_Float16)(a1 * sc);
  *reinterpret_cast<half2v*>(N + (size_t)n * 128 + lane * 2) = o;
}

// ---------------- aggregation: fp16 H (D=256) -> fp16 N [NN][256] ----------------
__global__ __launch_bounds__(256) void k_agg16(const _Float16* __restrict__ H,
                                               const int* __restrict__ rowptr,
                                               const int* __restrict__ col,
                                               _Float16* __restrict__ N) {
  const int lane = threadIdx.x & 63;
  const int n = blockIdx.x * 4 + (threadIdx.x >> 6);
  if (n >= NN) return;
  const int start = rowptr[n];
  const int end = rowptr[n + 1];
  float a0 = 0.f, a1 = 0.f, a2 = 0.f, a3 = 0.f;
  for (int base = start; base < end; base += 64) {
    int e = base + lane;
    int c = (e < end) ? col[e] : 0;
    int m = min(64, end - base);
    int t = 0;
    for (; t + 3 < m; t += 4) {
      int c0 = __shfl(c, t), c1 = __shfl(c, t + 1), c2 = __shfl(c, t + 2), c3 = __shfl(c, t + 3);
      half4v v0 = *reinterpret_cast<const half4v*>(H + (size_t)c0 * 256 + lane * 4);
      half4v v1 = *reinterpret_cast<const half4v*>(H + (size_t)c1 * 256 + lane * 4);
      half4v v2 = *reinterpret_cast<const half4v*>(H + (size_t)c2 * 256 + lane * 4);
      half4v v3 = *reinterpret_cast<const half4v*>(H + (size_t)c3 * 256 + lane * 4);
      a0 += (float)v0[0] + (float)v1[0] + (float)v2[0] + (float)v3[0];
      a1 += (float)v0[1] + (float)v1[1] + (float)v2[1] + (float)v3[1];
      a2 += (float)v0[2] + (float)v1[2] + (float)v2[2] + (float)v3[2];
      a3 += (float)v0[3] + (float)v1[3] + (float)v2[3] + (float)v3[3];
    }
    for (; t < m; ++t) {
      int cs = __shfl(c, t);
      half4v v = *reinterpret_cast<const half4v*>(H + (size_t)cs * 256 + lane * 4);
      a0 += (float)v[0];
      a1 += (float)v[1];
      a2 += (float)v[2];
      a3 += (float)v[3];
    }
  }
  int deg = end - start;
  float sc = 1.0f / (float)(deg > 0 ? deg : 1);
  half4v o;
  o[0] = (_Float16)(a0 * sc);
  o[1] = (_Float16)(a1 * sc);
  o[2] = (_Float16)(a2 * sc);
  o[3] = (_Float16)(a3 * sc);
  *reinterpret_cast<half4v*>(N + (size_t)n * 256 + lane * 4) = o;
}

// ---------------- fp16 MFMA dual-GEMM, counted-vmcnt pipeline ----------------
// A1,A2: [NN][K] fp16 row-major. W1p,W2p: fragment-major packed (k_wpack).
// LDS per buffer: A frags [4][512] + B frags [16][512] = 10240 halfs (20 KB), dbuf.
// Per step each thread issues EXACTLY 5 global_load_lds (1 A + 4 B) -> vmcnt(5)
// waits the previous stage while the newest stays in flight (T3+T4 minimal).
__global__ __launch_bounds__(256) void k_mfma16(
    const _Float16* __restrict__ A1, const _Float16* __restrict__ A2,
    const _Float16* __restrict__ W1p, const _Float16* __restrict__ W2p,
    const float* __restrict__ bias, int K,
    _Float16* __restrict__ outH, float* __restrict__ outF) {
  __shared__ _Float16 LDS[20480];  // 40 KB: 2 pipeline bufs; reused as 64x264 out tile
  const int tid = threadIdx.x;
  const int w = tid >> 6;
  const int lane = tid & 63;
  const int lrow = lane & 15;
  const int kg8 = (lane >> 4) * 8;
  const int m0 = blockIdx.x * 64;
  const int nk = K >> 5;
  const int nsteps = nk * 2;

  f32x4 acc[4][4];
#pragma unroll
  for (int i = 0; i < 4; ++i)
#pragma unroll
    for (int j = 0; j < 4; ++j) acc[i][j] = (f32x4){0.f, 0.f, 0.f, 0.f};

  int arowi = m0 + w * 16 + lrow;
  const size_t arow = (size_t)(arowi < NN ? arowi : NN - 1);

#define STAGE(S, B)                                                            \
  {                                                                            \
    const _Float16* Ap = ((S) >= nk) ? A2 : A1;                                \
    const _Float16* Wp = ((S) >= nk) ? W2p : W1p;                              \
    const int sl = ((S) >= nk) ? (S) - nk : (S);                               \
    gload_lds16(Ap + arow * K + (sl << 5) + kg8,                               \
                (void*)&LDS[(B) * 10240 + w * 512]);                           \
    const _Float16* wsrc = Wp + (size_t)(sl * 16 + w * 4) * 512 + lane * 8;    \
    _Pragma("unroll") for (int j = 0; j < 4; ++j)                              \
        gload_lds16(wsrc + j * 512,                                            \
                    (void*)&LDS[(B) * 10240 + 2048 + (w * 4 + j) * 512]);      \
  }

#define COMPUTE(B)                                                             \
  {                                                                            \
    half8v af[4];                                                              \
    _Pragma("unroll") for (int rf = 0; rf < 4; ++rf)                           \
        af[rf] = *reinterpret_cast<const half8v*>(                             \
            &LDS[(B) * 10240 + rf * 512 + lane * 8]);                          \
    _Pragma("unroll") for (int cf = 0; cf < 4; ++cf) {                         \
      half8v bf = *reinterpret_cast<const half8v*>(                            \
          &LDS[(B) * 10240 + 2048 + (w * 4 + cf) * 512 + lane * 8]);           \
      _Pragma("unroll") for (int rf = 0; rf < 4; ++rf)                         \
          acc[rf][cf] = __builtin_amdgcn_mfma_f32_16x16x32_f16(                \
              af[rf], bf, acc[rf][cf], 0, 0, 0);                               \
    }                                                                          \
  }

  STAGE(0, 0);
  STAGE(1, 1);
  vm_wait5();  // stage(0) complete; stage(1) in flight
  barx();
  for (int s = 0; s < nsteps; ++s) {
    COMPUTE(s & 1);
    barx();  // all waves done reading buf (ds reads drained via MFMA deps)
    if (s + 2 < nsteps) {
      STAGE(s + 2, s & 1);
      vm_wait5();  // stage(s+1) complete; stage(s+2) in flight
    } else {
      vm_wait0();  // tail: final stage complete
    }
    barx();
  }
#undef STAGE
#undef COMPUTE

  const int rquad = (lane >> 4) * 4;
  if (outF) {
#pragma unroll
    for (int cf = 0; cf < 4; ++cf) {
      const int colc = w * 64 + cf * 16 + lrow;
      const float bb = bias[colc];
#pragma unroll
      for (int rf = 0; rf < 4; ++rf)
#pragma unroll
        for (int j = 0; j < 4; ++j) {
          const int row = m0 + rf * 16 + rquad + j;
          if (row < NN) {
            float v = acc[rf][cf][j] + bb;
            outF[(size_t)row * 256 + colc] = v > 0.f ? v : 0.f;
          }
        }
    }
  } else {
    // stage tile in LDS (stride 264), then coalesced 16B stores
#pragma unroll
    for (int cf = 0; cf < 4; ++cf) {
      const int colc = w * 64 + cf * 16 + lrow;
      const float bb = bias[colc];
#pragma unroll
      for (int rf = 0; rf < 4; ++rf)
#pragma unroll
        for (int j = 0; j < 4; ++j) {
          float v = acc[rf][cf][j] + bb;
          LDS[(rf * 16 + rquad + j) * 264 + colc] = (_Float16)(v > 0.f ? v : 0.f);
        }
    }
    __syncthreads();
    const int row = tid >> 2;
    const int q = tid & 3;
    if (m0 + row < NN) {
#pragma unroll
      for (int it = 0; it < 8; ++it)
        *reinterpret_cast<half8v*>(outH + (size_t)(m0 + row) * 256 + q * 64 + it * 8) =
            *reinterpret_cast<const half8v*>(&LDS[row * 264 + q * 64 + it * 8]);
    }
  }
}

extern "C" void kernel_launch(void* const* d_in, const int* in_sizes, int n_in,
                              void* d_out, int out_size, void* d_ws, size_t ws_size,
                              hipStream_t stream) {
  const float* x   = (const float*)d_in[0];
  const int* src   = (const int*)d_in[1];
  const int* dst   = (const int*)d_in[2];
  const float* Ws0 = (const float*)d_in[3];
  const float* Wn0 = (const float*)d_in[4];
  const float* b0  = (const float*)d_in[5];
  const float* Ws1 = (const float*)d_in[6];
  const float* Wn1 = (const float*)d_in[7];
  const float* b1  = (const float*)d_in[8];
  const float* Ws2 = (const float*)d_in[9];
  const float* Wn2 = (const float*)d_in[10];
  const float* b2  = (const float*)d_in[11];
  float* out = (float*)d_out;

  char* ws = (char*)d_ws;
  size_t off = 0;
  auto alloc = [&](size_t bytes) {
    void* p = ws + off;
    off = (off + bytes + 255) & ~(size_t)255;
    return p;
  };
  _Float16* X16 = (_Float16*)alloc((size_t)NN * 128 * 2);
  _Float16* H   = (_Float16*)alloc((size_t)NN * 256 * 2);
  _Float16* Nb  = (_Float16*)alloc((size_t)NN * 256 * 2);
  int* rowptr = (int*)alloc((size_t)(NN + 1) * sizeof(int));
  int* cnt    = (int*)alloc((size_t)NN * sizeof(int));
  int* col    = (int*)alloc((size_t)NE * sizeof(int));
  _Float16* W0s = (_Float16*)alloc(256 * 128 * 2);
  _Float16* W0n = (_Float16*)alloc(256 * 128 * 2);
  _Float16* W1s = (_Float16*)alloc(256 * 256 * 2);
  _Float16* W1n = (_Float16*)alloc(256 * 256 * 2);
  _Float16* W2s = (_Float16*)alloc(256 * 256 * 2);
  _Float16* W2n = (_Float16*)alloc(256 * 256 * 2);

  // CSR build
  k_zero<<<(NN + 1023) / 1024, 1024, 0, stream>>>(cnt, NN);
  k_count<<<1024, 256, 0, stream>>>(dst, cnt);
  k_scan<<<1, 1024, 0, stream>>>(cnt, rowptr);
  k_fill<<<1024, 256, 0, stream>>>(src, dst, cnt, col);

  // weight prep (fragment-major pack, fp16)
  k_wpack<<<16, 256, 0, stream>>>(Ws0, W0s, 128);
  k_wpack<<<16, 256, 0, stream>>>(Wn0, W0n, 128);
  k_wpack<<<32, 256, 0, stream>>>(Ws1, W1s, 256);
  k_wpack<<<32, 256, 0, stream>>>(Wn1, W1n, 256);
  k_wpack<<<32, 256, 0, stream>>>(Ws2, W2s, 256);
  k_wpack<<<32, 256, 0, stream>>>(Wn2, W2n, 256);

  // x -> fp16
  k_split16<<<(NN * 16 + 255) / 256, 256, 0, stream>>>(x, X16);

  const int aggGrid = (NN + 3) / 4;
  const int gemmGrid = (NN + 63) / 64;

  // layer 0 (K=128)
  k_agg_x16<<<aggGrid, 256, 0, stream>>>(x, rowptr, col, Nb);
  k_mfma16<<<gemmGrid, 256, 0, stream>>>(X16, Nb, W0s, W0n, b0, 128, H, nullptr);
  // layer 1 (K=256)
  k_agg16<<<aggGrid, 256, 0, stream>>>(H, rowptr, col, Nb);
  k_mfma16<<<gemmGrid, 256, 0, stream>>>(H, Nb, W1s, W1n, b1, 256, H, nullptr);
  // layer 2 (K=256) -> fp32 out
  k_agg16<<<aggGrid, 256, 0, stream>>>(H, rowptr, col, Nb);
  k_mfma16<<<gemmGrid, 256, 0, stream>>>(H, Nb, W2s, W2n, b2, 256, nullptr, out);
}